// Round 2
// baseline (6951.644 us; speedup 1.0000x reference)
//
#include <hip/hip_runtime.h>
#include <hip/hip_bf16.h>

// RGCN 2-layer graph encoder.
// R2: relation-bucketed edge processing with LDS-staged W_r.
//   - counting-sort edges by relation into 256-edge-aligned buckets (perm)
//   - each block = one relation chunk: W_r staged once in LDS (64 KB max)
//   - 8 edges in flight per block (32 lanes x 4 cols each), float4 LDS reads
//   - per-edge scaled atomic scatter to h_acc[dst] (unchanged from R1)

#define N_NODES 50000
#define N_EDGES 1200000
#define N_REL   40
#define N_BASES 30
#define EMB     64
#define HID     128
#define N_GRAPHS 64

#define EPB     256   // edges per bucket-chunk / per block
#define PERM_CAP ((size_t)(N_EDGES + N_REL * EPB))          // upper bound incl. padding
#define NBLK    ((int)((PERM_CAP + EPB - 1) / EPB))         // edge-kernel grid

// ---------------- workspace layout (float units) ----------------
#define OFF_W1    ((size_t)0)                          // 40*64*128
#define OFF_W2    (OFF_W1 + (size_t)N_REL*EMB*HID)     // 40*128*128
#define OFF_CNT   (OFF_W2 + (size_t)N_REL*HID*HID)     // N*R
#define OFF_H1    (OFF_CNT + (size_t)N_NODES*N_REL)    // N*HID
#define OFF_H2    (OFF_H1 + (size_t)N_NODES*HID)       // N*HID
#define OFF_CNTG  (OFF_H2 + (size_t)N_NODES*HID)       // G
#define OFF_POOL  (OFF_CNTG + N_GRAPHS)                // G*HID
#define OFF_PERM  (OFF_POOL + (size_t)N_GRAPHS*HID)    // PERM_CAP ints
#define OFF_HIST  (OFF_PERM + PERM_CAP)                // 64 ints
#define OFF_CUR   (OFF_HIST + 64)                      // 64 ints
#define OFF_PO    (OFF_CUR + 64)                       // 64 ints (N_REL+1 used)

// W[r,i,o] = sum_b comp[r,b] * basis[b,i,o]
__global__ void k_compute_W(const float* __restrict__ comp,
                            const float* __restrict__ basis,
                            float* __restrict__ W, int IO) {
    int idx = blockIdx.x * blockDim.x + threadIdx.x;
    int total = N_REL * IO;
    if (idx >= total) return;
    int r = idx / IO, io = idx - r * IO;
    float s = 0.f;
#pragma unroll
    for (int b = 0; b < N_BASES; ++b)
        s += comp[r * N_BASES + b] * basis[(size_t)b * IO + io];
    W[idx] = s;
}

__global__ void k_count(const int* __restrict__ dst, const int* __restrict__ etype,
                        float* __restrict__ cnt) {
    int e = blockIdx.x * blockDim.x + threadIdx.x;
    if (e >= N_EDGES) return;
    atomicAdd(&cnt[(size_t)dst[e] * N_REL + etype[e]], 1.0f);
}

// ---- relation bucketing ----
__global__ void k_hist(const int* __restrict__ etype, int* __restrict__ hist) {
    __shared__ int lh[N_REL];
    if (threadIdx.x < N_REL) lh[threadIdx.x] = 0;
    __syncthreads();
    int e = blockIdx.x * blockDim.x + threadIdx.x;
    if (e < N_EDGES) atomicAdd(&lh[etype[e]], 1);
    __syncthreads();
    if (threadIdx.x < N_REL) atomicAdd(&hist[threadIdx.x], lh[threadIdx.x]);
}

__global__ void k_scan(const int* __restrict__ hist, int* __restrict__ po) {
    if (threadIdx.x == 0) {
        int acc = 0;
        for (int r = 0; r < N_REL; ++r) {
            po[r] = acc;
            acc += ((hist[r] + EPB - 1) / EPB) * EPB;  // pad each bucket to EPB
        }
        po[N_REL] = acc;
    }
}

__global__ void k_scatter_perm(const int* __restrict__ etype, const int* __restrict__ po,
                               int* __restrict__ cur, int* __restrict__ perm) {
    int e = blockIdx.x * blockDim.x + threadIdx.x;
    if (e >= N_EDGES) return;
    int r = etype[e];
    int pos = atomicAdd(&cur[r], 1);
    perm[po[r] + pos] = e;
}

// h_acc[n, o] = bias[o] + sum_i hin[row(n), i] * root[i, o]
template <int IN>
__global__ void k_root(const float* __restrict__ hin, const int* __restrict__ xmap,
                       const float* __restrict__ root, const float* __restrict__ bias,
                       float* __restrict__ hacc) {
    int n = blockIdx.x;
    int o = threadIdx.x;  // 128
    int row = xmap ? xmap[n] : n;
    const float* hr = hin + (size_t)row * IN;
    float s = bias[o];
#pragma unroll 8
    for (int i = 0; i < IN; ++i)
        s = fmaf(hr[i], root[i * HID + o], s);
    hacc[(size_t)n * HID + o] = s;
}

// relation-bucketed edge transform: W_r in LDS, 8 edges in flight.
template <int IN>
__global__ __launch_bounds__(256, 2)
void k_edge2(const float* __restrict__ hin, const int* __restrict__ xmap,
             const int* __restrict__ src, const int* __restrict__ dst,
             const int* __restrict__ perm, const int* __restrict__ po,
             const float* __restrict__ W, const float* __restrict__ cnt,
             float* __restrict__ hacc) {
    __shared__ float Wl[IN * HID];
    __shared__ float hst[8][IN + 4];   // +4 pad: spread group base across banks
    __shared__ int   mdst[8];
    __shared__ float minv[8];

    int s0 = blockIdx.x * EPB;
    int total = po[N_REL];
    if (s0 >= total) return;
    int r = 0;
    while (po[r + 1] <= s0) ++r;   // uniform scalar scan over <=40 buckets

    // stage W_r -> LDS (coalesced float4)
    {
        const float4* Wg = (const float4*)(W + (size_t)r * IN * HID);
        float4* Wl4 = (float4*)Wl;
        for (int k = threadIdx.x; k < IN * HID / 4; k += 256) Wl4[k] = Wg[k];
    }
    __syncthreads();

    int g = threadIdx.x >> 5;       // edge-group 0..7
    int l = threadIdx.x & 31;       // lane within group: 4 output cols

    for (int b0 = 0; b0 < EPB; b0 += 8) {
        int e = perm[s0 + b0 + g];
        if (e >= 0) {
            // stage h[src] row + per-edge meta (all within one 32-lane group,
            // i.e. one wave half -> no block barrier needed, lgkmcnt orders it)
            int sn = src[e];
            int row = xmap ? xmap[sn] : sn;
            const float4* hr4 = (const float4*)(hin + (size_t)row * IN);
            if (IN == 64) { if (l < 16) ((float4*)hst[g])[l] = hr4[l]; }
            else          { ((float4*)hst[g])[l] = hr4[l]; }
            if (l == 0) {
                int d = dst[e];
                mdst[g] = d;
                minv[g] = 1.0f / fmaxf(cnt[(size_t)d * N_REL + r], 1.0f);
            }

            float4 acc = {0.f, 0.f, 0.f, 0.f};
            const float* hrow = hst[g];
#pragma unroll 4
            for (int i = 0; i < IN; i += 4) {
                float4 hv = *(const float4*)(hrow + i);
                const float* wb = Wl + i * HID + (l << 2);
                float4 w;
                w = *(const float4*)(wb);
                acc.x = fmaf(hv.x, w.x, acc.x); acc.y = fmaf(hv.x, w.y, acc.y);
                acc.z = fmaf(hv.x, w.z, acc.z); acc.w = fmaf(hv.x, w.w, acc.w);
                w = *(const float4*)(wb + HID);
                acc.x = fmaf(hv.y, w.x, acc.x); acc.y = fmaf(hv.y, w.y, acc.y);
                acc.z = fmaf(hv.y, w.z, acc.z); acc.w = fmaf(hv.y, w.w, acc.w);
                w = *(const float4*)(wb + 2 * HID);
                acc.x = fmaf(hv.z, w.x, acc.x); acc.y = fmaf(hv.z, w.y, acc.y);
                acc.z = fmaf(hv.z, w.z, acc.z); acc.w = fmaf(hv.z, w.w, acc.w);
                w = *(const float4*)(wb + 3 * HID);
                acc.x = fmaf(hv.w, w.x, acc.x); acc.y = fmaf(hv.w, w.y, acc.y);
                acc.z = fmaf(hv.w, w.z, acc.z); acc.w = fmaf(hv.w, w.w, acc.w);
            }
            float inv = minv[g];
            float* dp = hacc + (size_t)mdst[g] * HID + (l << 2);
            atomicAdd(dp + 0, acc.x * inv);
            atomicAdd(dp + 1, acc.y * inv);
            atomicAdd(dp + 2, acc.z * inv);
            atomicAdd(dp + 3, acc.w * inv);
        }
    }
}

__global__ void k_relu(float* __restrict__ h, size_t n) {
    size_t i = (size_t)blockIdx.x * blockDim.x + threadIdx.x;
    if (i < n) h[i] = fmaxf(h[i], 0.0f);
}

// batch sorted -> per-graph node counts by binary search (no atomics)
__global__ void k_gcount2(const int* __restrict__ batch, float* __restrict__ cntG) {
    int g = threadIdx.x;
    if (g >= N_GRAPHS) return;
    int lo = 0, hi = N_NODES;
    while (lo < hi) { int m = (lo + hi) >> 1; if (batch[m] < g) lo = m + 1; else hi = m; }
    int lb0 = lo;
    lo = 0; hi = N_NODES;
    while (lo < hi) { int m = (lo + hi) >> 1; if (batch[m] < g + 1) lo = m + 1; else hi = m; }
    cntG[g] = (float)(lo - lb0);
}

// batch sorted: running per-column sum, flush on graph change
__global__ void k_pool(const float* __restrict__ h, const int* __restrict__ batch,
                       float* __restrict__ acc) {
    const int CH = 512;
    int n0 = blockIdx.x * CH;
    int o = threadIdx.x;  // 128
    int nend = min(n0 + CH, N_NODES);
    if (n0 >= N_NODES) return;
    int curg = batch[n0];
    float run = 0.f;
    for (int n = n0; n < nend; ++n) {
        int g = batch[n];
        if (g != curg) {
            atomicAdd(&acc[(size_t)curg * HID + o], run);
            run = 0.f;
            curg = g;
        }
        run += h[(size_t)n * HID + o];
    }
    atomicAdd(&acc[(size_t)curg * HID + o], run);
}

__global__ void k_final(const float* __restrict__ acc, const float* __restrict__ cntG,
                        float* __restrict__ out) {
    int idx = blockIdx.x * blockDim.x + threadIdx.x;
    if (idx >= N_GRAPHS * HID) return;
    int g = idx >> 7;
    out[idx] = acc[idx] / fmaxf(cntG[g], 1.0f);
}

extern "C" void kernel_launch(void* const* d_in, const int* in_sizes, int n_in,
                              void* d_out, int out_size, void* d_ws, size_t ws_size,
                              hipStream_t stream) {
    const int*   x         = (const int*)d_in[0];
    const int*   edge_index= (const int*)d_in[1];
    const int*   etype     = (const int*)d_in[2];
    const int*   batch     = (const int*)d_in[3];
    const float* node_emb  = (const float*)d_in[4];
    const float* comp1     = (const float*)d_in[5];
    const float* basis1    = (const float*)d_in[6];
    const float* root1     = (const float*)d_in[7];
    const float* bias1     = (const float*)d_in[8];
    const float* comp2     = (const float*)d_in[9];
    const float* basis2    = (const float*)d_in[10];
    const float* root2     = (const float*)d_in[11];
    const float* bias2     = (const float*)d_in[12];
    float* out = (float*)d_out;

    const int* src = edge_index;
    const int* dst = edge_index + N_EDGES;

    float* ws   = (float*)d_ws;
    float* W1   = ws + OFF_W1;
    float* W2   = ws + OFF_W2;
    float* cnt  = ws + OFF_CNT;
    float* h1   = ws + OFF_H1;
    float* h2   = ws + OFF_H2;
    float* cntG = ws + OFF_CNTG;
    float* pool = ws + OFF_POOL;
    int*   perm = (int*)(ws + OFF_PERM);
    int*   hist = (int*)(ws + OFF_HIST);
    int*   cur  = (int*)(ws + OFF_CUR);
    int*   po   = (int*)(ws + OFF_PO);

    // zero / init accumulators (h1/h2 fully written by k_root first)
    hipMemsetAsync(cnt, 0, (size_t)N_NODES * N_REL * sizeof(float), stream);
    hipMemsetAsync(cntG, 0, (size_t)(N_GRAPHS + N_GRAPHS * HID) * sizeof(float), stream);
    hipMemsetAsync(hist, 0, 128 * sizeof(int), stream);              // hist + cur
    hipMemsetAsync(perm, 0xFF, PERM_CAP * sizeof(int), stream);      // -1 padding

    // relation bucketing
    k_hist<<<(N_EDGES + 255) / 256, 256, 0, stream>>>(etype, hist);
    k_scan<<<1, 64, 0, stream>>>(hist, po);
    k_scatter_perm<<<(N_EDGES + 255) / 256, 256, 0, stream>>>(etype, po, cur, perm);

    // per (dst, rel) edge counts
    k_count<<<(N_EDGES + 255) / 256, 256, 0, stream>>>(dst, etype, cnt);

    // weights from basis decomposition
    k_compute_W<<<(N_REL * EMB * HID + 255) / 256, 256, 0, stream>>>(comp1, basis1, W1, EMB * HID);
    k_compute_W<<<(N_REL * HID * HID + 255) / 256, 256, 0, stream>>>(comp2, basis2, W2, HID * HID);

    // ---- layer 1 ----
    k_root<EMB><<<N_NODES, HID, 0, stream>>>(node_emb, x, root1, bias1, h1);
    k_edge2<EMB><<<NBLK, 256, 0, stream>>>(node_emb, x, src, dst, perm, po, W1, cnt, h1);
    k_relu<<<(N_NODES * HID + 255) / 256, 256, 0, stream>>>(h1, (size_t)N_NODES * HID);

    // ---- layer 2 ----
    k_root<HID><<<N_NODES, HID, 0, stream>>>(h1, nullptr, root2, bias2, h2);
    k_edge2<HID><<<NBLK, 256, 0, stream>>>(h1, nullptr, src, dst, perm, po, W2, cnt, h2);
    k_relu<<<(N_NODES * HID + 255) / 256, 256, 0, stream>>>(h2, (size_t)N_NODES * HID);

    // ---- global mean pool ----
    k_gcount2<<<1, 64, 0, stream>>>(batch, cntG);
    k_pool<<<(N_NODES + 511) / 512, HID, 0, stream>>>(h2, batch, pool);
    k_final<<<(N_GRAPHS * HID + 255) / 256, 256, 0, stream>>>(pool, cntG, out);
}

// Round 3
// 1542.668 us; speedup vs baseline: 4.5062x; 4.5062x over previous
//
#include <hip/hip_runtime.h>

// RGCN 2-layer graph encoder — R3: MFMA gather-GEMM edge kernel.
//  - edges counting-sorted by relation (block-aggregated scatter, low contention)
//  - W_r generated directly in bf16 MFMA B-fragment order; staged once in LDS
//  - wave = 16 edges: A-frags gathered from bf16 h copy (64B granules),
//    mfma_f32_16x16x32_bf16 accumulate f32, coalesced 64B atomic scatter
//  - h kept in f32 for root path; bf16 shadow copy (hb) for edge path

#define N_NODES 50000
#define N_EDGES 1200000
#define N_REL   40
#define N_BASES 30
#define EMB     64
#define HID     128
#define N_GRAPHS 64

#define EPB     256
#define PERM_CAP ((size_t)(N_EDGES + N_REL * EPB))
#define NBLK    ((int)((PERM_CAP + EPB - 1) / EPB))

typedef float f32x4  __attribute__((ext_vector_type(4)));
typedef short bf16x8 __attribute__((ext_vector_type(8)));

__device__ __forceinline__ unsigned short f2bf(float x) {
    unsigned int u = __float_as_uint(x);
    u = (u + 0x7FFFu + ((u >> 16) & 1u)) >> 16;   // RNE
    return (unsigned short)u;
}

// ---------------- workspace layout (float units) ----------------
#define OFF_WF1   ((size_t)0)                            // R*EMB*HID bf16 = 163840 f
#define OFF_WF2   (OFF_WF1 + (size_t)N_REL*EMB*HID/2)    // R*HID*HID bf16 = 327680 f
#define OFF_CNT   (OFF_WF2 + (size_t)N_REL*HID*HID/2)    // N*R f
#define OFF_H1    (OFF_CNT + (size_t)N_NODES*N_REL)      // N*HID f
#define OFF_H2    (OFF_H1 + (size_t)N_NODES*HID)         // N*HID f
#define OFF_HB    (OFF_H2 + (size_t)N_NODES*HID)         // N*HID bf16 (shared L1/L2 A-src)
#define OFF_CNTG  (OFF_HB + (size_t)N_NODES*HID/2)       // G
#define OFF_POOL  (OFF_CNTG + N_GRAPHS)                  // G*HID
#define OFF_PERM  (OFF_POOL + (size_t)N_GRAPHS*HID)      // PERM_CAP ints
#define OFF_HIST  (OFF_PERM + PERM_CAP)                  // 64 ints
#define OFF_CUR   (OFF_HIST + 64)                        // 64 ints
#define OFF_PO    (OFF_CUR + 64)                         // 64 ints

// ---- W fragment generator: Wf[r][((ct*KT+kt)*64+lane)*8+j] =
//      bf16( sum_b comp[r,b]*basis[b, kt*32+(lane>>4)*8+j, ct*16+(lane&15)] )
template <int IN, int KT>
__global__ void k_Wfrag(const float* __restrict__ comp, const float* __restrict__ basis,
                        unsigned short* __restrict__ Wf) {
    const int FR = IN * HID;
    int idx = blockIdx.x * blockDim.x + threadIdx.x;
    if (idx >= N_REL * FR) return;
    int r = idx / FR, F = idx - r * FR;
    int j = F & 7, lane = (F >> 3) & 63, tt = F >> 9;
    int kt = tt % KT, ct = tt / KT;
    int k = kt * 32 + (lane >> 4) * 8 + j;
    int c = ct * 16 + (lane & 15);
    float s = 0.f;
#pragma unroll
    for (int b = 0; b < N_BASES; ++b)
        s += comp[r * N_BASES + b] * basis[((size_t)b * IN + k) * HID + c];
    Wf[idx] = f2bf(s);
}

__global__ void k_count(const int* __restrict__ dst, const int* __restrict__ etype,
                        float* __restrict__ cnt) {
    int e = blockIdx.x * blockDim.x + threadIdx.x;
    if (e >= N_EDGES) return;
    atomicAdd(&cnt[(size_t)dst[e] * N_REL + etype[e]], 1.0f);
}

// ---- relation bucketing ----
__global__ void k_hist(const int* __restrict__ etype, int* __restrict__ hist) {
    __shared__ int lh[N_REL];
    if (threadIdx.x < N_REL) lh[threadIdx.x] = 0;
    __syncthreads();
    int e = blockIdx.x * blockDim.x + threadIdx.x;
    if (e < N_EDGES) atomicAdd(&lh[etype[e]], 1);
    __syncthreads();
    if (threadIdx.x < N_REL) atomicAdd(&hist[threadIdx.x], lh[threadIdx.x]);
}

__global__ void k_scan(const int* __restrict__ hist, int* __restrict__ po) {
    if (threadIdx.x == 0) {
        int acc = 0;
        for (int r = 0; r < N_REL; ++r) {
            po[r] = acc;
            acc += ((hist[r] + EPB - 1) / EPB) * EPB;
        }
        po[N_REL] = acc;
    }
}

// block-aggregated scatter: LDS hist -> 1 range-reservation atomic per (rel,block)
#define SP_EPB 1024
__global__ void k_scatter_perm2(const int* __restrict__ etype, const int* __restrict__ po,
                                int* __restrict__ cur, int* __restrict__ perm) {
    __shared__ int lh[N_REL], sbase[N_REL];
    int t = threadIdx.x;  // 256
    if (t < N_REL) lh[t] = 0;
    __syncthreads();
    int e0 = blockIdx.x * SP_EPB;
    int e_[4], r_[4];
#pragma unroll
    for (int i = 0; i < 4; ++i) {
        int e = e0 + t + i * 256;
        e_[i] = e;
        if (e < N_EDGES) { r_[i] = etype[e]; atomicAdd(&lh[r_[i]], 1); }
    }
    __syncthreads();
    if (t < N_REL) { sbase[t] = atomicAdd(&cur[t], lh[t]); lh[t] = 0; }
    __syncthreads();
#pragma unroll
    for (int i = 0; i < 4; ++i) {
        if (e_[i] < N_EDGES) {
            int p = atomicAdd(&lh[r_[i]], 1);
            perm[po[r_[i]] + sbase[r_[i]] + p] = e_[i];
        }
    }
}

// h_acc[n, o] = bias[o] + sum_i hin[row(n), i] * root[i, o]
template <int IN>
__global__ void k_root(const float* __restrict__ hin, const int* __restrict__ xmap,
                       const float* __restrict__ root, const float* __restrict__ bias,
                       float* __restrict__ hacc) {
    int n = blockIdx.x;
    int o = threadIdx.x;  // 128
    int row = xmap ? xmap[n] : n;
    const float* hr = hin + (size_t)row * IN;
    float s = bias[o];
#pragma unroll 8
    for (int i = 0; i < IN; ++i)
        s = fmaf(hr[i], root[i * HID + o], s);
    hacc[(size_t)n * HID + o] = s;
}

// ---- MFMA edge kernel: wave = 16 edges x 128 cols ----
// A: lane l holds h[edge(l&15)][kt*32 + (l>>4)*8 + j]   (16B global gather)
// B: fragment-ordered W in LDS, contiguous ds_read_b128
// C: lane l, reg q -> row (l>>4)*4+q (edge), col l&15 (+ct*16)
template <int IN, int KT>
__global__ __launch_bounds__(256, 4)
void k_edge3(const unsigned short* __restrict__ hb, const int* __restrict__ src,
             const int* __restrict__ dst, const int* __restrict__ perm,
             const int* __restrict__ po, const unsigned short* __restrict__ Wf,
             const float* __restrict__ cnt, float* __restrict__ hacc) {
    __shared__ unsigned short Wl[8 * KT * 64 * 8];
    int s0 = blockIdx.x * EPB;
    int total = po[N_REL];
    if (s0 >= total) return;
    int r = 0;
    while (po[r + 1] <= s0) ++r;

    {   // stage W_r fragments -> LDS (contiguous float4 copy)
        const f32x4* Wg = (const f32x4*)(Wf + (size_t)r * (8 * KT * 64 * 8));
        f32x4* Wd = (f32x4*)Wl;
        const int n16 = 8 * KT * 64;  // 16B chunks
        for (int kk = threadIdx.x; kk < n16; kk += 256) Wd[kk] = Wg[kk];
    }
    __syncthreads();

    int l = threadIdx.x & 63;
    int wv = threadIdx.x >> 6;
    int lrow = l & 15;
    int lk = l >> 4;

    for (int t = wv; t < EPB / 16; t += 4) {
        int base = s0 + t * 16;
        int ev = perm[base + lrow];      // lanes sharing lrow broadcast-load
        int rowA = 0, dv = 0;
        float inv = 0.f;
        if (ev >= 0) {
            rowA = src[ev];
            dv = dst[ev];
            inv = 1.0f / fmaxf(cnt[(size_t)dv * N_REL + r], 1.0f);
        }
        bf16x8 a[KT];
        const unsigned short* hrow = hb + (size_t)rowA * IN + lk * 8;
#pragma unroll
        for (int kt = 0; kt < KT; ++kt)
            a[kt] = *(const bf16x8*)(hrow + kt * 32);

        f32x4 acc[8];
#pragma unroll
        for (int ct = 0; ct < 8; ++ct) acc[ct] = (f32x4){0.f, 0.f, 0.f, 0.f};
#pragma unroll
        for (int ct = 0; ct < 8; ++ct) {
#pragma unroll
            for (int kt = 0; kt < KT; ++kt) {
                bf16x8 b = *(const bf16x8*)(Wl + ((ct * KT + kt) * 64 + l) * 8);
                acc[ct] = __builtin_amdgcn_mfma_f32_16x16x32_bf16(a[kt], b, acc[ct], 0, 0, 0);
            }
        }
        // scatter: per (q,ct) instruction writes one full 64B line per 16-lane group
#pragma unroll
        for (int q = 0; q < 4; ++q) {
            int row = lk * 4 + q;
            int e_q = __shfl(ev, row);
            if (e_q >= 0) {
                int d_q   = __shfl(dv, row);
                float i_q = __shfl(inv, row);
                float* dp = hacc + (size_t)d_q * HID + lrow;
#pragma unroll
                for (int ct = 0; ct < 8; ++ct)
                    atomicAdd(dp + ct * 16, acc[ct][q] * i_q);
            }
        }
    }
}

// layer-1 A source: hb[n][:] = bf16(node_emb[x[n]][:])
__global__ void k_cvt_emb(const float* __restrict__ emb, const int* __restrict__ x,
                          unsigned short* __restrict__ hb) {
    int idx = blockIdx.x * blockDim.x + threadIdx.x;
    if (idx >= N_NODES * (EMB / 4)) return;
    int n = idx / (EMB / 4), c4 = idx % (EMB / 4);
    int row = x[n];
    float4 v = *(const float4*)(emb + (size_t)row * EMB + c4 * 4);
    ushort4 o = {f2bf(v.x), f2bf(v.y), f2bf(v.z), f2bf(v.w)};
    *(ushort4*)(hb + (size_t)n * EMB + c4 * 4) = o;
}

// relu in place + bf16 shadow write
__global__ void k_relu_cvt(float* __restrict__ h, unsigned short* __restrict__ hb,
                           int n4) {
    int i = blockIdx.x * blockDim.x + threadIdx.x;
    if (i >= n4) return;
    float4 v = ((float4*)h)[i];
    v.x = fmaxf(v.x, 0.f); v.y = fmaxf(v.y, 0.f);
    v.z = fmaxf(v.z, 0.f); v.w = fmaxf(v.w, 0.f);
    ((float4*)h)[i] = v;
    ushort4 o = {f2bf(v.x), f2bf(v.y), f2bf(v.z), f2bf(v.w)};
    ((ushort4*)hb)[i] = o;
}

__global__ void k_relu(float* __restrict__ h, size_t n) {
    size_t i = (size_t)blockIdx.x * blockDim.x + threadIdx.x;
    if (i < n) h[i] = fmaxf(h[i], 0.0f);
}

__global__ void k_gcount2(const int* __restrict__ batch, float* __restrict__ cntG) {
    int g = threadIdx.x;
    if (g >= N_GRAPHS) return;
    int lo = 0, hi = N_NODES;
    while (lo < hi) { int m = (lo + hi) >> 1; if (batch[m] < g) lo = m + 1; else hi = m; }
    int lb0 = lo;
    lo = 0; hi = N_NODES;
    while (lo < hi) { int m = (lo + hi) >> 1; if (batch[m] < g + 1) lo = m + 1; else hi = m; }
    cntG[g] = (float)(lo - lb0);
}

__global__ void k_pool(const float* __restrict__ h, const int* __restrict__ batch,
                       float* __restrict__ acc) {
    const int CH = 512;
    int n0 = blockIdx.x * CH;
    int o = threadIdx.x;  // 128
    int nend = min(n0 + CH, N_NODES);
    if (n0 >= N_NODES) return;
    int curg = batch[n0];
    float run = 0.f;
    for (int n = n0; n < nend; ++n) {
        int g = batch[n];
        if (g != curg) {
            atomicAdd(&acc[(size_t)curg * HID + o], run);
            run = 0.f;
            curg = g;
        }
        run += h[(size_t)n * HID + o];
    }
    atomicAdd(&acc[(size_t)curg * HID + o], run);
}

__global__ void k_final(const float* __restrict__ acc, const float* __restrict__ cntG,
                        float* __restrict__ out) {
    int idx = blockIdx.x * blockDim.x + threadIdx.x;
    if (idx >= N_GRAPHS * HID) return;
    int g = idx >> 7;
    out[idx] = acc[idx] / fmaxf(cntG[g], 1.0f);
}

extern "C" void kernel_launch(void* const* d_in, const int* in_sizes, int n_in,
                              void* d_out, int out_size, void* d_ws, size_t ws_size,
                              hipStream_t stream) {
    const int*   x         = (const int*)d_in[0];
    const int*   edge_index= (const int*)d_in[1];
    const int*   etype     = (const int*)d_in[2];
    const int*   batch     = (const int*)d_in[3];
    const float* node_emb  = (const float*)d_in[4];
    const float* comp1     = (const float*)d_in[5];
    const float* basis1    = (const float*)d_in[6];
    const float* root1     = (const float*)d_in[7];
    const float* bias1     = (const float*)d_in[8];
    const float* comp2     = (const float*)d_in[9];
    const float* basis2    = (const float*)d_in[10];
    const float* root2     = (const float*)d_in[11];
    const float* bias2     = (const float*)d_in[12];
    float* out = (float*)d_out;

    const int* src = edge_index;
    const int* dst = edge_index + N_EDGES;

    float* ws = (float*)d_ws;
    unsigned short* Wf1 = (unsigned short*)(ws + OFF_WF1);
    unsigned short* Wf2 = (unsigned short*)(ws + OFF_WF2);
    float* cnt  = ws + OFF_CNT;
    float* h1   = ws + OFF_H1;
    float* h2   = ws + OFF_H2;
    unsigned short* hb = (unsigned short*)(ws + OFF_HB);
    float* cntG = ws + OFF_CNTG;
    float* pool = ws + OFF_POOL;
    int*   perm = (int*)(ws + OFF_PERM);
    int*   hist = (int*)(ws + OFF_HIST);
    int*   cur  = (int*)(ws + OFF_CUR);
    int*   po   = (int*)(ws + OFF_PO);

    hipMemsetAsync(cnt, 0, (size_t)N_NODES * N_REL * sizeof(float), stream);
    hipMemsetAsync(cntG, 0, (size_t)(N_GRAPHS + N_GRAPHS * HID) * sizeof(float), stream);
    hipMemsetAsync(hist, 0, 128 * sizeof(int), stream);
    hipMemsetAsync(perm, 0xFF, PERM_CAP * sizeof(int), stream);

    // relation bucketing (block-aggregated reservation)
    k_hist<<<(N_EDGES + 255) / 256, 256, 0, stream>>>(etype, hist);
    k_scan<<<1, 64, 0, stream>>>(hist, po);
    k_scatter_perm2<<<(N_EDGES + SP_EPB - 1) / SP_EPB, 256, 0, stream>>>(etype, po, cur, perm);

    k_count<<<(N_EDGES + 255) / 256, 256, 0, stream>>>(dst, etype, cnt);

    // fragment-ordered bf16 weights
    k_Wfrag<EMB, 2><<<(N_REL * EMB * HID + 255) / 256, 256, 0, stream>>>(comp1, basis1, Wf1);
    k_Wfrag<HID, 4><<<(N_REL * HID * HID + 255) / 256, 256, 0, stream>>>(comp2, basis2, Wf2);

    // ---- layer 1 ----
    k_cvt_emb<<<(N_NODES * (EMB / 4) + 255) / 256, 256, 0, stream>>>(node_emb, x, hb);
    k_root<EMB><<<N_NODES, HID, 0, stream>>>(node_emb, x, root1, bias1, h1);
    k_edge3<EMB, 2><<<NBLK, 256, 0, stream>>>(hb, src, dst, perm, po, Wf1, cnt, h1);
    k_relu_cvt<<<(N_NODES * HID / 4 + 255) / 256, 256, 0, stream>>>(h1, hb, N_NODES * HID / 4);

    // ---- layer 2 ----
    k_root<HID><<<N_NODES, HID, 0, stream>>>(h1, nullptr, root2, bias2, h2);
    k_edge3<HID, 4><<<NBLK, 256, 0, stream>>>(hb, src, dst, perm, po, Wf2, cnt, h2);
    k_relu<<<(N_NODES * HID + 255) / 256, 256, 0, stream>>>(h2, (size_t)N_NODES * HID);

    // ---- global mean pool ----
    k_gcount2<<<1, 64, 0, stream>>>(batch, cntG);
    k_pool<<<(N_NODES + 511) / 512, HID, 0, stream>>>(h2, batch, pool);
    k_final<<<(N_GRAPHS * HID + 255) / 256, 256, 0, stream>>>(pool, cntG, out);
}